// Round 4
// baseline (313.031 us; speedup 1.0000x reference)
//
#include <hip/hip_runtime.h>
#include <hip/hip_bf16.h>
#include <math.h>

#define NN   10000
#define HIDD 512
#define BP   4096
#define KPAD 10048      // 157 * 64
#define KITER1 157
#define KSPLIT 4

typedef short bf16x8 __attribute__((ext_vector_type(8)));
typedef float f32x4  __attribute__((ext_vector_type(4)));
typedef unsigned short u16x4 __attribute__((ext_vector_type(4)));
typedef unsigned short u16x8 __attribute__((ext_vector_type(8)));

__device__ __forceinline__ unsigned short f2bf(float f) {
  union { float f; unsigned u; } v; v.f = f;
  unsigned r = v.u + 0x7FFFu + ((v.u >> 16) & 1u);   // RN-even
  return (unsigned short)(r >> 16);
}
__device__ __forceinline__ float bf2f(unsigned short u) {
  union { unsigned u; float f; } v; v.u = ((unsigned)u) << 16;
  return v.f;
}
__device__ __forceinline__ void gload_lds16(const void* g, void* l) {
  __builtin_amdgcn_global_load_lds((const __attribute__((address_space(1))) unsigned int*)g,
                                   (__attribute__((address_space(3))) unsigned int*)l, 16, 0, 0);
}

// src f32 [K][512] -> dst bf16 [512][Kpadw], zero-padded for k in [K, Kpadw)
__global__ void transpose_cvt(const float* __restrict__ src, unsigned short* __restrict__ dst,
                              int K, int Kpadw) {
  __shared__ float tile[32][33];
  int k0 = blockIdx.x * 32, n0 = blockIdx.y * 32;
  int t = threadIdx.x, c = t & 31, r = t >> 5;
  #pragma unroll
  for (int i = 0; i < 4; ++i) {
    int k = k0 + r + i * 8;
    float v = (k < K) ? src[(size_t)k * 512 + (n0 + c)] : 0.f;
    tile[r + i * 8][c] = v;
  }
  __syncthreads();
  #pragma unroll
  for (int i = 0; i < 4; ++i) {
    int n = n0 + r + i * 8;
    dst[(size_t)n * Kpadw + (k0 + c)] = f2bf(tile[c][r + i * 8]);
  }
}

// Gather-GEMM, 2-phase pipelined (raw s_barrier + counted vmcnt):
// Block tile 256(m) x 256(n) x BK=64; 8 waves (2m x 4n), wave-tile 128x64.
// A: reg-staged f32->bf16, single LDS buffer (write phase / read phase split by barrier).
// B: double-buffered LDS via global_load_lds, swizzle folded into global source addr;
//    B(t+1) issued at iter start, waited with vmcnt(8) under the MFMA phase.
// vmcnt ledger per wave/iter: issue B(t+1)=4 instrs, then A(t+1)=8 instrs -> 12 outstanding.
//   end of iter: vmcnt(8) -> oldest 4 (B) complete, A still in flight.
//   top of next iter: vmcnt(0) -> A regs ready for cvt.
__global__ __launch_bounds__(512, 2)
void gather_gemm(const float* __restrict__ A, const unsigned short* __restrict__ BT,
                 float* __restrict__ Ppart,
                 const int* __restrict__ idxx, const int* __restrict__ idxy) {
  __shared__ __align__(16) char As[256 * 128];      // 256 rows x 64 bf16, XOR-swizzled granules
  __shared__ __align__(16) char Bs[2][256 * 128];   // dbuf, swizzle via pre-swizzled source
  const int tid  = threadIdx.x;
  const int lane = tid & 63;
  const int wave = tid >> 6;            // 0..7
  const int wm   = wave >> 2;           // 0..1 -> m offset wm*128
  const int wn   = wave & 3;            // 0..3 -> n offset wn*64
  const int nk   = blockIdx.x;          // 0..7 ; id%8 = nk -> one (nblk,ksp) per XCD
  const int nblk = nk & 1, ksp = nk >> 1;
  const int m0   = blockIdx.y * 256;
  const int n0   = nblk * 256;
  const int t0   = (ksp * KITER1) / KSPLIT;
  const int t1   = ((ksp + 1) * KITER1) / KSPLIT;

  // A staging: 2 threads/row; thread covers k-half sp*32..+32 (8 float4 loads)
  const int sr = tid >> 1, sp = tid & 1;
  int m = m0 + sr;
  int g = (m < BP) ? idxx[m] : idxy[m - BP];
  const float* arow = A + (size_t)g * NN;

  // B staging: per wave 4 gload_lds chunks c = wave*4+j, each 1 KB = 8 rows.
  // lane covers row n0 + c*8 + (lane>>3), LDS slot lane&7 <- global granule (lane&7)^(lane>>3).
  const unsigned short* bsrc0 =
      BT + (size_t)(n0 + (wave << 5) + (lane >> 3)) * KPAD + (((lane & 7) ^ (lane >> 3)) << 3);

  f32x4 acc[8][4];
  #pragma unroll
  for (int i = 0; i < 8; ++i)
    #pragma unroll
    for (int j = 0; j < 4; ++j) acc[i][j] = (f32x4){0.f, 0.f, 0.f, 0.f};

  float4 ar[8];

  auto LOADA = [&](int t) {
    int kb = t * 64 + sp * 32;
    #pragma unroll
    for (int j = 0; j < 8; ++j) {
      int ka = kb + j * 4;
      if (ka < NN) ar[j] = *(const float4*)(arow + ka);
      else         ar[j] = make_float4(0.f, 0.f, 0.f, 0.f);
    }
  };
  auto ISSUEB = [&](int t, int buf) {
    const unsigned short* s = bsrc0 + (size_t)t * 64;
    char* d = Bs[buf] + (wave << 12);
    #pragma unroll
    for (int j = 0; j < 4; ++j)
      gload_lds16(s + (size_t)j * 8 * KPAD, d + j * 1024);
  };
  auto WRITEA = [&]() {
    #pragma unroll
    for (int q = 0; q < 4; ++q) {
      u16x8 o;
      o[0] = f2bf(ar[2*q].x);   o[1] = f2bf(ar[2*q].y);
      o[2] = f2bf(ar[2*q].z);   o[3] = f2bf(ar[2*q].w);
      o[4] = f2bf(ar[2*q+1].x); o[5] = f2bf(ar[2*q+1].y);
      o[6] = f2bf(ar[2*q+1].z); o[7] = f2bf(ar[2*q+1].w);
      int gq = sp * 4 + q;
      *(u16x8*)(As + sr * 128 + ((gq ^ (sr & 7)) << 4)) = o;
    }
  };

  LOADA(t0);
  ISSUEB(t0, 0);
  int cur = 0;
  for (int t = t0; t < t1; ++t) {
    // ---- phase W: A regs -> LDS; issue next-tile loads ----
    asm volatile("s_waitcnt vmcnt(0)" ::: "memory");   // A(t) regs (and, first iter, B(t0))
    __builtin_amdgcn_sched_barrier(0);
    WRITEA();
    const bool more = (t + 1 < t1);
    if (more) {
      ISSUEB(t + 1, cur ^ 1);     // 4 vmem, land under MFMA phase
      LOADA(t + 1);               // 8 vmem, land by next phase W
    }
    asm volatile("s_waitcnt lgkmcnt(0)" ::: "memory"); // A ds_writes done
    __builtin_amdgcn_sched_barrier(0);
    __builtin_amdgcn_s_barrier();                      // As(t), Bs[cur](t) visible to all
    __builtin_amdgcn_sched_barrier(0);
    // ---- phase C: compute ----
    const char* Bc = Bs[cur];
    #pragma unroll
    for (int ks = 0; ks < 2; ++ks) {
      int kg = ks * 4 + (lane >> 4);
      bf16x8 bfr[4];
      #pragma unroll
      for (int j = 0; j < 4; ++j) {
        int n = wn * 64 + j * 16 + (lane & 15);
        bfr[j] = *(const bf16x8*)(Bc + n * 128 + ((kg ^ (n & 7)) << 4));
      }
      #pragma unroll
      for (int i = 0; i < 8; ++i) {
        int r = wm * 128 + i * 16 + (lane & 15);
        bf16x8 af = *(const bf16x8*)(As + r * 128 + ((kg ^ (r & 7)) << 4));
        #pragma unroll
        for (int j = 0; j < 4; ++j)
          acc[i][j] = __builtin_amdgcn_mfma_f32_16x16x32_bf16(af, bfr[j], acc[i][j], 0, 0, 0);
      }
    }
    if (more) {
      asm volatile("s_waitcnt vmcnt(8)" ::: "memory"); // B(t+1) landed; A(t+1) still flying
    }
    __builtin_amdgcn_sched_barrier(0);
    __builtin_amdgcn_s_barrier();                      // readers done with As(t)/Bs[cur]
    __builtin_amdgcn_sched_barrier(0);
    cur ^= 1;
  }

  float* Cb = Ppart + (size_t)ksp * (8192 * 512);
  #pragma unroll
  for (int i = 0; i < 8; ++i) {
    #pragma unroll
    for (int j = 0; j < 4; ++j) {
      int row = m0 + wm * 128 + i * 16 + ((lane >> 4) << 2);
      int col = n0 + wn * 64 + j * 16 + (lane & 15);
      #pragma unroll
      for (int rr = 0; rr < 4; ++rr)
        Cb[(size_t)(row + rr) * 512 + col] = acc[i][j][rr];
    }
  }
}

// Fused highway layer: h = x@Wh + bh, g = x@Wg + bg in one tile pass;
// epilogue: xout = relu(h)*sigmoid(g) + x*(1-sigmoid(g)), bf16.
__global__ __launch_bounds__(256)
void hwy_gemm(const unsigned short* __restrict__ xin, const unsigned short* __restrict__ WcT,
              const float* __restrict__ bh, const float* __restrict__ bg,
              unsigned short* __restrict__ xout) {
  __shared__ __align__(16) char As[128 * 128];
  __shared__ __align__(16) char Bs[128 * 128];   // rows 0-63: Wh^T n0+..; 64-127: Wg^T 512+n0+..
  const int tid  = threadIdx.x;
  const int lane = tid & 63;
  const int wave = tid >> 6;
  const int wm = wave >> 1, wn = wave & 1;
  const int m0 = blockIdx.y * 128;
  const int n0 = blockIdx.x * 64;

  const int sr = tid >> 1, sp = tid & 1;
  const unsigned short* arow16 = xin + (size_t)(m0 + sr) * HIDD;
  const int rb = tid >> 1;
  const int grow = (rb < 64) ? (n0 + rb) : (512 + n0 + rb - 64);
  const unsigned short* brow = WcT + (size_t)grow * HIDD;

  f32x4 acc[4][2][2];
  #pragma unroll
  for (int i = 0; i < 4; ++i)
    #pragma unroll
    for (int j = 0; j < 2; ++j)
      #pragma unroll
      for (int p = 0; p < 2; ++p) acc[i][j][p] = (f32x4){0.f, 0.f, 0.f, 0.f};

  u16x8 ar16[4], br16[4];

  auto LOADREGS = [&](int t) {
    int k0 = t * 64;
    #pragma unroll
    for (int j = 0; j < 4; ++j)
      ar16[j] = *(const u16x8*)(arow16 + k0 + (sp * 4 + j) * 8);
    #pragma unroll
    for (int q = 0; q < 4; ++q)
      br16[q] = *(const u16x8*)(brow + k0 + (sp * 4 + q) * 8);
  };
  auto WRITELDS = [&]() {
    #pragma unroll
    for (int j = 0; j < 4; ++j) {
      int gq = sp * 4 + j;
      *(u16x8*)(As + sr * 128 + ((gq ^ (sr & 7)) << 4)) = ar16[j];
    }
    #pragma unroll
    for (int q = 0; q < 4; ++q) {
      int gq = sp * 4 + q;
      *(u16x8*)(Bs + rb * 128 + ((gq ^ (rb & 7)) << 4)) = br16[q];
    }
  };

  for (int t = 0; t < 8; ++t) {
    if (t == 0) LOADREGS(0);
    else __syncthreads();
    WRITELDS();
    if (t + 1 < 8) LOADREGS(t + 1);
    __syncthreads();
    #pragma unroll
    for (int ks = 0; ks < 2; ++ks) {
      bf16x8 af[4]; bf16x8 bfr[2][2];
      int kg = ks * 4 + (lane >> 4);
      #pragma unroll
      for (int i = 0; i < 4; ++i) {
        int r = wm * 64 + i * 16 + (lane & 15);
        af[i] = *(const bf16x8*)(As + r * 128 + ((kg ^ (r & 7)) << 4));
      }
      #pragma unroll
      for (int j = 0; j < 2; ++j)
        #pragma unroll
        for (int p = 0; p < 2; ++p) {
          int n = p * 64 + wn * 32 + j * 16 + (lane & 15);
          bfr[j][p] = *(const bf16x8*)(Bs + n * 128 + ((kg ^ (n & 7)) << 4));
        }
      #pragma unroll
      for (int i = 0; i < 4; ++i)
        #pragma unroll
        for (int j = 0; j < 2; ++j)
          #pragma unroll
          for (int p = 0; p < 2; ++p)
            acc[i][j][p] = __builtin_amdgcn_mfma_f32_16x16x32_bf16(af[i], bfr[j][p], acc[i][j][p], 0, 0, 0);
    }
  }

  #pragma unroll
  for (int j = 0; j < 2; ++j) {
    int col = n0 + wn * 32 + j * 16 + (lane & 15);
    float bhv = bh[col], bgv = bg[col];
    #pragma unroll
    for (int i = 0; i < 4; ++i) {
      int row = m0 + wm * 64 + i * 16 + ((lane >> 4) << 2);
      #pragma unroll
      for (int rr = 0; rr < 4; ++rr) {
        float hv = fmaxf(acc[i][j][0][rr] + bhv, 0.f);
        float gv = acc[i][j][1][rr] + bgv;
        float tv = 1.f / (1.f + expf(-gv));
        float xi = bf2f(xin[(size_t)(row + rr) * HIDD + col]);
        xout[(size_t)(row + rr) * HIDD + col] = f2bf(hv * tv + xi * (1.f - tv));
      }
    }
  }
}

// ex = relu(sum of KSPLIT partials), rows [0,4096)=ex, [4096,8192)=ey
__global__ void pair_combine(const float* __restrict__ P, unsigned short* __restrict__ xb) {
  int i = blockIdx.x * 256 + threadIdx.x;       // 4096*512/4 float4 groups
  const size_t qs = (size_t)8192 * 512 / 4;
  const size_t yoff = (size_t)BP * HIDD / 4;
  float4 a = ((const float4*)P)[i];
  float4 b = ((const float4*)P)[i + yoff];
  #pragma unroll
  for (int q = 1; q < KSPLIT; ++q) {
    float4 aq = ((const float4*)P)[i + q * qs];
    float4 bq = ((const float4*)P)[i + yoff + q * qs];
    a.x += aq.x; a.y += aq.y; a.z += aq.z; a.w += aq.w;
    b.x += bq.x; b.y += bq.y; b.z += bq.z; b.w += bq.w;
  }
  const float s = 0.04419417382415922f;    // 1/sqrt(512)
  float ex, ey, d;
  u16x4 o;
  ex = fmaxf(a.x, 0.f); ey = fmaxf(b.x, 0.f); d = ex - ey; o[0] = f2bf(d * d * s);
  ex = fmaxf(a.y, 0.f); ey = fmaxf(b.y, 0.f); d = ex - ey; o[1] = f2bf(d * d * s);
  ex = fmaxf(a.z, 0.f); ey = fmaxf(b.z, 0.f); d = ex - ey; o[2] = f2bf(d * d * s);
  ex = fmaxf(a.w, 0.f); ey = fmaxf(b.w, 0.f); d = ex - ey; o[3] = f2bf(d * d * s);
  ((u16x4*)xb)[i] = o;
}

// logits + 2-class log_softmax, one wave per row
__global__ void logits_lsm(const unsigned short* __restrict__ x2, const float* __restrict__ Wl,
                           const float* __restrict__ bl, float* __restrict__ out) {
  int gw = (blockIdx.x * blockDim.x + threadIdx.x) >> 6;
  int lane = threadIdx.x & 63;
  const unsigned short* xr = x2 + (size_t)gw * HIDD;
  u16x8 xv = *(const u16x8*)(xr + lane * 8);
  float4 w0 = ((const float4*)Wl)[lane * 4 + 0];
  float4 w1 = ((const float4*)Wl)[lane * 4 + 1];
  float4 w2 = ((const float4*)Wl)[lane * 4 + 2];
  float4 w3 = ((const float4*)Wl)[lane * 4 + 3];
  float xs[8];
  #pragma unroll
  for (int j = 0; j < 8; ++j) xs[j] = bf2f(xv[j]);
  float s0 = xs[0]*w0.x + xs[1]*w0.z + xs[2]*w1.x + xs[3]*w1.z
           + xs[4]*w2.x + xs[5]*w2.z + xs[6]*w3.x + xs[7]*w3.z;
  float s1 = xs[0]*w0.y + xs[1]*w0.w + xs[2]*w1.y + xs[3]*w1.w
           + xs[4]*w2.y + xs[5]*w2.w + xs[6]*w3.y + xs[7]*w3.w;
  #pragma unroll
  for (int off = 32; off; off >>= 1) { s0 += __shfl_down(s0, off); s1 += __shfl_down(s1, off); }
  if (lane == 0) {
    float l0 = s0 + bl[0], l1 = s1 + bl[1];
    float mx = fmaxf(l0, l1);
    float lse = mx + logf(expf(l0 - mx) + expf(l1 - mx));
    out[(size_t)gw * 2 + 0] = l0 - lse;
    out[(size_t)gw * 2 + 1] = l1 - lse;
  }
}

extern "C" void kernel_launch(void* const* d_in, const int* in_sizes, int n_in,
                              void* d_out, int out_size, void* d_ws, size_t ws_size,
                              hipStream_t stream) {
  const float* A   = (const float*)d_in[0];
  const float* W1  = (const float*)d_in[1];
  const float* Wh0 = (const float*)d_in[2];
  const float* bh0 = (const float*)d_in[3];
  const float* Wg0 = (const float*)d_in[4];
  const float* bg0 = (const float*)d_in[5];
  const float* Wh1 = (const float*)d_in[6];
  const float* bh1 = (const float*)d_in[7];
  const float* Wg1 = (const float*)d_in[8];
  const float* bg1 = (const float*)d_in[9];
  const float* Wl  = (const float*)d_in[10];
  const float* bl  = (const float*)d_in[11];
  const int* idxx  = (const int*)d_in[12];
  const int* idxy  = (const int*)d_in[13];
  float* out = (float*)d_out;

  char* w = (char*)d_ws;
  auto carve = [&](size_t bytes) { char* p = w; w += (bytes + 255) & ~(size_t)255; return p; };
  unsigned short* W1T  = (unsigned short*)carve((size_t)512 * KPAD * 2);
  unsigned short* WcT0 = (unsigned short*)carve((size_t)1024 * 512 * 2);
  unsigned short* WcT1 = (unsigned short*)carve((size_t)1024 * 512 * 2);
  float* Ppart         = (float*)carve((size_t)KSPLIT * 8192 * 512 * 4);
  unsigned short* xb0  = (unsigned short*)carve((size_t)4096 * 512 * 2);
  unsigned short* xb1  = (unsigned short*)carve((size_t)4096 * 512 * 2);
  unsigned short* xb2  = (unsigned short*)carve((size_t)4096 * 512 * 2);

  // weight prep (~31 MB traffic)
  transpose_cvt<<<dim3(KPAD / 32, 16), 256, 0, stream>>>(W1, W1T, NN, KPAD);
  transpose_cvt<<<dim3(16, 16), 256, 0, stream>>>(Wh0, WcT0, 512, 512);
  transpose_cvt<<<dim3(16, 16), 256, 0, stream>>>(Wg0, WcT0 + (size_t)512 * 512, 512, 512);
  transpose_cvt<<<dim3(16, 16), 256, 0, stream>>>(Wh1, WcT1, 512, 512);
  transpose_cvt<<<dim3(16, 16), 256, 0, stream>>>(Wg1, WcT1 + (size_t)512 * 512, 512, 512);

  // Ppart[ksp] = A[gathered rows] @ W1 K-chunk; grid x = (nblk,ksp) -> 8, y = m -> 32
  gather_gemm<<<dim3(8, 32), 512, 0, stream>>>(A, W1T, Ppart, idxx, idxy);
  pair_combine<<<dim3(2048), 256, 0, stream>>>(Ppart, xb0);

  // fused highway layers
  hwy_gemm<<<dim3(8, 32), 256, 0, stream>>>(xb0, WcT0, bh0, bg0, xb1);
  hwy_gemm<<<dim3(8, 32), 256, 0, stream>>>(xb1, WcT1, bh1, bg1, xb2);

  logits_lsm<<<dim3(1024), 256, 0, stream>>>(xb2, Wl, bl, out);
}

// Round 5
// 205.900 us; speedup vs baseline: 1.5203x; 1.5203x over previous
//
#include <hip/hip_runtime.h>
#include <hip/hip_bf16.h>
#include <math.h>

#define NN   10000
#define HIDD 512
#define BP   4096
#define KPAD 10048      // 157 * 64
#define KITER1 157
#define KSPLIT 4

typedef short bf16x8 __attribute__((ext_vector_type(8)));
typedef float f32x4  __attribute__((ext_vector_type(4)));
typedef unsigned short u16x4 __attribute__((ext_vector_type(4)));
typedef unsigned short u16x8 __attribute__((ext_vector_type(8)));

__device__ __forceinline__ unsigned short f2bf(float f) {
  union { float f; unsigned u; } v; v.f = f;
  unsigned r = v.u + 0x7FFFu + ((v.u >> 16) & 1u);   // RN-even
  return (unsigned short)(r >> 16);
}
__device__ __forceinline__ float bf2f(unsigned short u) {
  union { unsigned u; float f; } v; v.u = ((unsigned)u) << 16;
  return v.f;
}
__device__ __forceinline__ void gload_lds16(const void* g, void* l) {
  __builtin_amdgcn_global_load_lds((const __attribute__((address_space(1))) unsigned int*)g,
                                   (__attribute__((address_space(3))) unsigned int*)l, 16, 0, 0);
}

// src f32 [K][512] -> dst bf16 [512][Kpadw], zero-padded for k in [K, Kpadw)
__global__ void transpose_cvt(const float* __restrict__ src, unsigned short* __restrict__ dst,
                              int K, int Kpadw) {
  __shared__ float tile[32][33];
  int k0 = blockIdx.x * 32, n0 = blockIdx.y * 32;
  int t = threadIdx.x, c = t & 31, r = t >> 5;
  #pragma unroll
  for (int i = 0; i < 4; ++i) {
    int k = k0 + r + i * 8;
    float v = (k < K) ? src[(size_t)k * 512 + (n0 + c)] : 0.f;
    tile[r + i * 8][c] = v;
  }
  __syncthreads();
  #pragma unroll
  for (int i = 0; i < 4; ++i) {
    int n = n0 + r + i * 8;
    dst[(size_t)n * Kpadw + (k0 + c)] = f2bf(tile[c][r + i * 8]);
  }
}

// Gather-GEMM: Ppart[ksp][8192][512] = A[gather rows] @ W1T^T over K-chunk ksp.
// Block tile 64(m) x 512(n) x BK=64; 256 threads = 4 waves, wave-tile 64x128.
// MFMA:LDS-read per SIMD-iter = 2483:576 cyc -> MFMA-bound; 72 KB LDS + <=256 VGPR
// -> 2 blocks/CU so one block's staging stall hides under the other's MFMA (m114).
// A rows read EXACTLY ONCE from HBM (BN = full 512). Simple 2-barrier loop,
// compiler-scheduled waits (round-3 discipline; no manual vmcnt pinning).
__global__ __launch_bounds__(256, 2)
void gather_gemm(const float* __restrict__ A, const unsigned short* __restrict__ BT,
                 float* __restrict__ Ppart,
                 const int* __restrict__ idxx, const int* __restrict__ idxy) {
  __shared__ __align__(16) char As[64 * 128];    // 64 rows x 64 bf16, XOR-swizzled granules
  __shared__ __align__(16) char Bs[512 * 128];   // 512 n-rows x 64 bf16, swizzle via src addr
  const int tid  = threadIdx.x;
  const int lane = tid & 63;
  const int wave = tid >> 6;            // 0..3, owns n-range [wave*128, +128)
  const int m0   = blockIdx.y * 64;
  const int ksp  = blockIdx.x;          // 0..3
  const int t0   = (ksp * KITER1) / KSPLIT;
  const int t1   = ((ksp + 1) * KITER1) / KSPLIT;

  // A staging: 4 threads/row, thread covers 16 consecutive floats (4 float4)
  const int sr = tid >> 2, sp = tid & 3;
  int m = m0 + sr;
  int g = (m < BP) ? idxx[m] : idxy[m - BP];
  const float* arow = A + (size_t)g * NN;

  // B staging: per wave 16 gload_lds chunks of 1 KB (8 rows); lane covers
  // row wave*128 + j*8 + (lane>>3), LDS slot lane&7 <- global granule (lane&7)^(lane>>3)
  const unsigned short* bsrc0 =
      BT + (size_t)(wave * 128 + (lane >> 3)) * KPAD + (((lane & 7) ^ (lane >> 3)) << 3);
  char* bdst0 = Bs + (wave << 14);

  f32x4 acc[4][8];
  #pragma unroll
  for (int i = 0; i < 4; ++i)
    #pragma unroll
    for (int j = 0; j < 8; ++j) acc[i][j] = (f32x4){0.f, 0.f, 0.f, 0.f};

  float4 ar[4];

  auto LOADA = [&](int t) {
    int kb = t * 64 + sp * 16;
    #pragma unroll
    for (int j = 0; j < 4; ++j) {
      int ka = kb + j * 4;
      if (ka < NN) ar[j] = *(const float4*)(arow + ka);
      else         ar[j] = make_float4(0.f, 0.f, 0.f, 0.f);
    }
  };
  auto ISSUEB = [&](int t) {
    const unsigned short* s = bsrc0 + (size_t)t * 64;
    #pragma unroll
    for (int j = 0; j < 16; ++j)
      gload_lds16(s + (size_t)j * 8 * KPAD, bdst0 + j * 1024);
  };
  auto WRITEA = [&]() {
    #pragma unroll
    for (int q = 0; q < 2; ++q) {
      u16x8 o;
      o[0] = f2bf(ar[2*q].x);   o[1] = f2bf(ar[2*q].y);
      o[2] = f2bf(ar[2*q].z);   o[3] = f2bf(ar[2*q].w);
      o[4] = f2bf(ar[2*q+1].x); o[5] = f2bf(ar[2*q+1].y);
      o[6] = f2bf(ar[2*q+1].z); o[7] = f2bf(ar[2*q+1].w);
      int gq = sp * 2 + q;
      *(u16x8*)(As + sr * 128 + ((gq ^ (sr & 7)) << 4)) = o;
    }
  };

  LOADA(t0);
  ISSUEB(t0);
  for (int t = t0; t < t1; ++t) {
    if (t > t0) __syncthreads();      // drains B(t) gloads; As writable again
    WRITEA();                         // compiler waits A(t) regs
    __syncthreads();                  // As(t), Bs(t) visible to all
    if (t + 1 < t1) LOADA(t + 1);     // A prefetch rides under compute
    #pragma unroll
    for (int ks = 0; ks < 2; ++ks) {
      int kg = ks * 4 + (lane >> 4);
      bf16x8 af[4]; bf16x8 bfr[8];
      #pragma unroll
      for (int i = 0; i < 4; ++i) {
        int r = i * 16 + (lane & 15);
        af[i] = *(const bf16x8*)(As + r * 128 + ((kg ^ (r & 7)) << 4));
      }
      #pragma unroll
      for (int j = 0; j < 8; ++j) {
        int n = wave * 128 + j * 16 + (lane & 15);
        bfr[j] = *(const bf16x8*)(Bs + n * 128 + ((kg ^ (n & 7)) << 4));
      }
      #pragma unroll
      for (int i = 0; i < 4; ++i)
        #pragma unroll
        for (int j = 0; j < 8; ++j)
          acc[i][j] = __builtin_amdgcn_mfma_f32_16x16x32_bf16(af[i], bfr[j], acc[i][j], 0, 0, 0);
    }
    __syncthreads();                  // all waves done reading LDS(t)
    if (t + 1 < t1) ISSUEB(t + 1);    // refill Bs for next iter
  }

  float* Cb = Ppart + (size_t)ksp * (8192 * 512);
  #pragma unroll
  for (int i = 0; i < 4; ++i) {
    #pragma unroll
    for (int j = 0; j < 8; ++j) {
      int row = m0 + i * 16 + ((lane >> 4) << 2);
      int col = wave * 128 + j * 16 + (lane & 15);
      #pragma unroll
      for (int rr = 0; rr < 4; ++rr)
        Cb[(size_t)(row + rr) * 512 + col] = acc[i][j][rr];
    }
  }
}

// Fused highway layer: h = x@Wh + bh, g = x@Wg + bg in one tile pass;
// epilogue: xout = relu(h)*sigmoid(g) + x*(1-sigmoid(g)), bf16.
__global__ __launch_bounds__(256)
void hwy_gemm(const unsigned short* __restrict__ xin, const unsigned short* __restrict__ WcT,
              const float* __restrict__ bh, const float* __restrict__ bg,
              unsigned short* __restrict__ xout) {
  __shared__ __align__(16) char As[128 * 128];
  __shared__ __align__(16) char Bs[128 * 128];   // rows 0-63: Wh^T n0+..; 64-127: Wg^T 512+n0+..
  const int tid  = threadIdx.x;
  const int lane = tid & 63;
  const int wave = tid >> 6;
  const int wm = wave >> 1, wn = wave & 1;
  const int m0 = blockIdx.y * 128;
  const int n0 = blockIdx.x * 64;

  const int sr = tid >> 1, sp = tid & 1;
  const unsigned short* arow16 = xin + (size_t)(m0 + sr) * HIDD;
  const int rb = tid >> 1;
  const int grow = (rb < 64) ? (n0 + rb) : (512 + n0 + rb - 64);
  const unsigned short* brow = WcT + (size_t)grow * HIDD;

  f32x4 acc[4][2][2];
  #pragma unroll
  for (int i = 0; i < 4; ++i)
    #pragma unroll
    for (int j = 0; j < 2; ++j)
      #pragma unroll
      for (int p = 0; p < 2; ++p) acc[i][j][p] = (f32x4){0.f, 0.f, 0.f, 0.f};

  u16x8 ar16[4], br16[4];

  auto LOADREGS = [&](int t) {
    int k0 = t * 64;
    #pragma unroll
    for (int j = 0; j < 4; ++j)
      ar16[j] = *(const u16x8*)(arow16 + k0 + (sp * 4 + j) * 8);
    #pragma unroll
    for (int q = 0; q < 4; ++q)
      br16[q] = *(const u16x8*)(brow + k0 + (sp * 4 + q) * 8);
  };
  auto WRITELDS = [&]() {
    #pragma unroll
    for (int j = 0; j < 4; ++j) {
      int gq = sp * 4 + j;
      *(u16x8*)(As + sr * 128 + ((gq ^ (sr & 7)) << 4)) = ar16[j];
    }
    #pragma unroll
    for (int q = 0; q < 4; ++q) {
      int gq = sp * 4 + q;
      *(u16x8*)(Bs + rb * 128 + ((gq ^ (rb & 7)) << 4)) = br16[q];
    }
  };

  for (int t = 0; t < 8; ++t) {
    if (t == 0) LOADREGS(0);
    else __syncthreads();
    WRITELDS();
    if (t + 1 < 8) LOADREGS(t + 1);
    __syncthreads();
    #pragma unroll
    for (int ks = 0; ks < 2; ++ks) {
      bf16x8 af[4]; bf16x8 bfr[2][2];
      int kg = ks * 4 + (lane >> 4);
      #pragma unroll
      for (int i = 0; i < 4; ++i) {
        int r = wm * 64 + i * 16 + (lane & 15);
        af[i] = *(const bf16x8*)(As + r * 128 + ((kg ^ (r & 7)) << 4));
      }
      #pragma unroll
      for (int j = 0; j < 2; ++j)
        #pragma unroll
        for (int p = 0; p < 2; ++p) {
          int n = p * 64 + wn * 32 + j * 16 + (lane & 15);
          bfr[j][p] = *(const bf16x8*)(Bs + n * 128 + ((kg ^ (n & 7)) << 4));
        }
      #pragma unroll
      for (int i = 0; i < 4; ++i)
        #pragma unroll
        for (int j = 0; j < 2; ++j)
          #pragma unroll
          for (int p = 0; p < 2; ++p)
            acc[i][j][p] = __builtin_amdgcn_mfma_f32_16x16x32_bf16(af[i], bfr[j][p], acc[i][j][p], 0, 0, 0);
    }
  }

  #pragma unroll
  for (int j = 0; j < 2; ++j) {
    int col = n0 + wn * 32 + j * 16 + (lane & 15);
    float bhv = bh[col], bgv = bg[col];
    #pragma unroll
    for (int i = 0; i < 4; ++i) {
      int row = m0 + wm * 64 + i * 16 + ((lane >> 4) << 2);
      #pragma unroll
      for (int rr = 0; rr < 4; ++rr) {
        float hv = fmaxf(acc[i][j][0][rr] + bhv, 0.f);
        float gv = acc[i][j][1][rr] + bgv;
        float tv = 1.f / (1.f + expf(-gv));
        float xi = bf2f(xin[(size_t)(row + rr) * HIDD + col]);
        xout[(size_t)(row + rr) * HIDD + col] = f2bf(hv * tv + xi * (1.f - tv));
      }
    }
  }
}

// ex = relu(sum of KSPLIT partials), rows [0,4096)=ex, [4096,8192)=ey
__global__ void pair_combine(const float* __restrict__ P, unsigned short* __restrict__ xb) {
  int i = blockIdx.x * 256 + threadIdx.x;       // 4096*512/4 float4 groups
  const size_t qs = (size_t)8192 * 512 / 4;
  const size_t yoff = (size_t)BP * HIDD / 4;
  float4 a = ((const float4*)P)[i];
  float4 b = ((const float4*)P)[i + yoff];
  #pragma unroll
  for (int q = 1; q < KSPLIT; ++q) {
    float4 aq = ((const float4*)P)[i + q * qs];
    float4 bq = ((const float4*)P)[i + yoff + q * qs];
    a.x += aq.x; a.y += aq.y; a.z += aq.z; a.w += aq.w;
    b.x += bq.x; b.y += bq.y; b.z += bq.z; b.w += bq.w;
  }
  const float s = 0.04419417382415922f;    // 1/sqrt(512)
  float ex, ey, d;
  u16x4 o;
  ex = fmaxf(a.x, 0.f); ey = fmaxf(b.x, 0.f); d = ex - ey; o[0] = f2bf(d * d * s);
  ex = fmaxf(a.y, 0.f); ey = fmaxf(b.y, 0.f); d = ex - ey; o[1] = f2bf(d * d * s);
  ex = fmaxf(a.z, 0.f); ey = fmaxf(b.z, 0.f); d = ex - ey; o[2] = f2bf(d * d * s);
  ex = fmaxf(a.w, 0.f); ey = fmaxf(b.w, 0.f); d = ex - ey; o[3] = f2bf(d * d * s);
  ((u16x4*)xb)[i] = o;
}

// logits + 2-class log_softmax, one wave per row
__global__ void logits_lsm(const unsigned short* __restrict__ x2, const float* __restrict__ Wl,
                           const float* __restrict__ bl, float* __restrict__ out) {
  int gw = (blockIdx.x * blockDim.x + threadIdx.x) >> 6;
  int lane = threadIdx.x & 63;
  const unsigned short* xr = x2 + (size_t)gw * HIDD;
  u16x8 xv = *(const u16x8*)(xr + lane * 8);
  float4 w0 = ((const float4*)Wl)[lane * 4 + 0];
  float4 w1 = ((const float4*)Wl)[lane * 4 + 1];
  float4 w2 = ((const float4*)Wl)[lane * 4 + 2];
  float4 w3 = ((const float4*)Wl)[lane * 4 + 3];
  float xs[8];
  #pragma unroll
  for (int j = 0; j < 8; ++j) xs[j] = bf2f(xv[j]);
  float s0 = xs[0]*w0.x + xs[1]*w0.z + xs[2]*w1.x + xs[3]*w1.z
           + xs[4]*w2.x + xs[5]*w2.z + xs[6]*w3.x + xs[7]*w3.z;
  float s1 = xs[0]*w0.y + xs[1]*w0.w + xs[2]*w1.y + xs[3]*w1.w
           + xs[4]*w2.y + xs[5]*w2.w + xs[6]*w3.y + xs[7]*w3.w;
  #pragma unroll
  for (int off = 32; off; off >>= 1) { s0 += __shfl_down(s0, off); s1 += __shfl_down(s1, off); }
  if (lane == 0) {
    float l0 = s0 + bl[0], l1 = s1 + bl[1];
    float mx = fmaxf(l0, l1);
    float lse = mx + logf(expf(l0 - mx) + expf(l1 - mx));
    out[(size_t)gw * 2 + 0] = l0 - lse;
    out[(size_t)gw * 2 + 1] = l1 - lse;
  }
}

extern "C" void kernel_launch(void* const* d_in, const int* in_sizes, int n_in,
                              void* d_out, int out_size, void* d_ws, size_t ws_size,
                              hipStream_t stream) {
  const float* A   = (const float*)d_in[0];
  const float* W1  = (const float*)d_in[1];
  const float* Wh0 = (const float*)d_in[2];
  const float* bh0 = (const float*)d_in[3];
  const float* Wg0 = (const float*)d_in[4];
  const float* bg0 = (const float*)d_in[5];
  const float* Wh1 = (const float*)d_in[6];
  const float* bh1 = (const float*)d_in[7];
  const float* Wg1 = (const float*)d_in[8];
  const float* bg1 = (const float*)d_in[9];
  const float* Wl  = (const float*)d_in[10];
  const float* bl  = (const float*)d_in[11];
  const int* idxx  = (const int*)d_in[12];
  const int* idxy  = (const int*)d_in[13];
  float* out = (float*)d_out;

  char* w = (char*)d_ws;
  auto carve = [&](size_t bytes) { char* p = w; w += (bytes + 255) & ~(size_t)255; return p; };
  unsigned short* W1T  = (unsigned short*)carve((size_t)512 * KPAD * 2);
  unsigned short* WcT0 = (unsigned short*)carve((size_t)1024 * 512 * 2);
  unsigned short* WcT1 = (unsigned short*)carve((size_t)1024 * 512 * 2);
  float* Ppart         = (float*)carve((size_t)KSPLIT * 8192 * 512 * 4);
  unsigned short* xb0  = (unsigned short*)carve((size_t)4096 * 512 * 2);
  unsigned short* xb1  = (unsigned short*)carve((size_t)4096 * 512 * 2);
  unsigned short* xb2  = (unsigned short*)carve((size_t)4096 * 512 * 2);

  // weight prep (~31 MB traffic)
  transpose_cvt<<<dim3(KPAD / 32, 16), 256, 0, stream>>>(W1, W1T, NN, KPAD);
  transpose_cvt<<<dim3(16, 16), 256, 0, stream>>>(Wh0, WcT0, 512, 512);
  transpose_cvt<<<dim3(16, 16), 256, 0, stream>>>(Wg0, WcT0 + (size_t)512 * 512, 512, 512);
  transpose_cvt<<<dim3(16, 16), 256, 0, stream>>>(Wh1, WcT1, 512, 512);
  transpose_cvt<<<dim3(16, 16), 256, 0, stream>>>(Wg1, WcT1 + (size_t)512 * 512, 512, 512);

  // Ppart[ksp] = A[gathered rows] @ W1 K-chunk; 512 blocks = 2/CU
  gather_gemm<<<dim3(KSPLIT, 128), 256, 0, stream>>>(A, W1T, Ppart, idxx, idxy);
  pair_combine<<<dim3(2048), 256, 0, stream>>>(Ppart, xb0);

  // fused highway layers
  hwy_gemm<<<dim3(8, 32), 256, 0, stream>>>(xb0, WcT0, bh0, bg0, xb1);
  hwy_gemm<<<dim3(8, 32), 256, 0, stream>>>(xb1, WcT1, bh1, bg1, xb2);

  logits_lsm<<<dim3(1024), 256, 0, stream>>>(xb2, Wl, bl, out);
}